// Round 5
// baseline (4428.064 us; speedup 1.0000x reference)
//
#include <hip/hip_runtime.h>
#include <stdint.h>

typedef unsigned short u16;
typedef __attribute__((ext_vector_type(8))) _Float16 f16x8;
typedef __attribute__((ext_vector_type(4))) float f32x4;

// ---------- helpers ----------
__device__ inline f16x8 ldfrag(const u16* p) { return *(const f16x8*)p; }
__device__ inline u16 f2h(float x) {
    _Float16 h = (_Float16)x;
    union { _Float16 h; u16 u; } v; v.h = h;
    return v.u;
}
__device__ inline float sigmoidf_(float x) { return 1.0f / (1.0f + expf(-x)); }

// Layouts (fp16 as u16):
//  A-frag (X: 256 x K):  AF[mtile][kb][lane][8]
//      = X[mtile*16 + (lane&15)][kb*32 + (lane>>4)*8 + j]
//  B-frag (W: N x K):    BF[grp][sub][kb][lane][8]
//      = W[row(grp,sub,lane)][kb*32 + (lane>>4)*8 + j],  row = sub*S1 + grp*S2 + (lane&15)
//  lstm:  S1=1024 (gate), S2=16 (ct)   -> BF[ct][gate][kb][..]
//  fc1:   S1=16,  S2=64                -> BF[ctq][nt ][kb][..]
//  fc2:   S1=16,  S2=0 (grp=0)         -> BF[0][nt][kb][..]
//
// ROW-PARTITIONED SCHEME (this round):
//  XCD x (= blockIdx%8, HW round-robin) owns rows [32x, 32x+32) = mtiles {2x, 2x+1}.
//  Block i (= blockIdx>>3, 0..31) owns 128 gate-cols = ct {2i, 2i+1}.
//  All activations XCD-private; intra-XCD barrier + buffer_inv sc0 (vL1) only.

struct PP {
    const u16* xyenc;
    u16* xdec;
    const u16 *wih0, *whh0, *wih1, *whh1, *fcw1, *fcw2;
    const float *b0s, *b1s, *fcb1, *fcb2, *pre_y;
    u16 *h0a, *h0b, *h1a, *h1b, *ufc;
    float* out;
    unsigned* bar;   // 8 XCDs x 128 u32 (cnt at +0, rel at +64)
};

// intra-XCD barrier: 32 blocks, monotonic epoch; relaxed agent atomics.
// On exit: invalidate this CU's vector L1 so cross-CU L2 data is seen fresh.
__device__ __forceinline__ void xbar(unsigned* cnt, unsigned* rel, unsigned ep) {
    __syncthreads();   // drains this block's vmem (stores visible in local L2)
    if (threadIdx.x == 0) {
        unsigned old = __hip_atomic_fetch_add(cnt, 1u, __ATOMIC_RELAXED,
                                              __HIP_MEMORY_SCOPE_AGENT);
        if (old == ep * 32u + 31u) {
            __hip_atomic_store(rel, ep + 1u, __ATOMIC_RELAXED,
                               __HIP_MEMORY_SCOPE_AGENT);
        } else {
            unsigned r;
            do {
                __builtin_amdgcn_s_sleep(2);
                r = __hip_atomic_load(rel, __ATOMIC_RELAXED,
                                      __HIP_MEMORY_SCOPE_AGENT);
            } while (r < ep + 1u);
        }
    }
    __syncthreads();
    asm volatile("buffer_inv sc0" ::: "memory");   // vL1 invalidate (gfx940+)
    __builtin_amdgcn_sched_barrier(0);
}

// stage A-frag segment [2 mtiles][KB][64][8] (mtiles mtbase, mtbase+1) into LDS.
static __device__ __forceinline__ void stage_seg(
    const u16* __restrict__ AF, int kbshift, int mtbase, u16* lds, int tid)
{
    const int KB = 1 << kbshift;
    const int n  = 2 << (kbshift + 6);   // #16B chunks
    for (int idx = tid; idx < n; idx += 512) {
        const int lane = idx & 63;
        const int kb   = (idx >> 6) & (KB - 1);
        const int mt   = idx >> (kbshift + 6);
        f16x8 v = ldfrag(AF + (((size_t)(mtbase + mt) * KB + kb) * 64 + lane) * 8);
        *(f16x8*)(lds + (size_t)idx * 8) = v;
    }
}

// ---------- LSTM phase (row-partitioned) ----------
static __device__ __forceinline__ void lstm2(
    const u16* __restrict__ AFa, int kbsa, const u16* __restrict__ BFa,
    const u16* __restrict__ AFh, const u16* __restrict__ BFh,
    const float* __restrict__ bsum, float* c2, u16* __restrict__ h_out,
    int xcd, int i, int w, int lane, int tid, u16* ldsA, f32x4 (*red)[2][64])
{
    const int mtbase = xcd * 2;
    const int KBa = 1 << kbsa;
    u16* ldsAh = ldsA + ((size_t)(2 << (kbsa + 6))) * 8;

    stage_seg(AFa, kbsa, mtbase, ldsA, tid);
    stage_seg(AFh, 5, mtbase, ldsAh, tid);
    __syncthreads();

    // wave w -> ct = 2i + (w>>2), gate g = w&3; full K; acc over 2 mtiles.
    const int ct = i * 2 + (w >> 2), g = w & 3;
    f32x4 acc0 = {0, 0, 0, 0}, acc1 = {0, 0, 0, 0};
    {
        const u16* bp = BFa + (((size_t)(ct * 4 + g) * KBa) * 64 + lane) * 8;
        #pragma unroll 4
        for (int kb = 0; kb < KBa; ++kb) {
            f16x8 b  = ldfrag(bp + (size_t)kb * 512);
            f16x8 a0 = *(const f16x8*)(ldsA + (((size_t)kb) * 64 + lane) * 8);
            f16x8 a1 = *(const f16x8*)(ldsA + (((size_t)KBa + kb) * 64 + lane) * 8);
            acc0 = __builtin_amdgcn_mfma_f32_16x16x32_f16(a0, b, acc0, 0, 0, 0);
            acc1 = __builtin_amdgcn_mfma_f32_16x16x32_f16(a1, b, acc1, 0, 0, 0);
        }
    }
    {
        const u16* bp = BFh + (((size_t)(ct * 4 + g) * 32) * 64 + lane) * 8;
        #pragma unroll 4
        for (int kb = 0; kb < 32; ++kb) {
            f16x8 b  = ldfrag(bp + (size_t)kb * 512);
            f16x8 a0 = *(const f16x8*)(ldsAh + (((size_t)kb) * 64 + lane) * 8);
            f16x8 a1 = *(const f16x8*)(ldsAh + (((size_t)32 + kb) * 64 + lane) * 8);
            acc0 = __builtin_amdgcn_mfma_f32_16x16x32_f16(a0, b, acc0, 0, 0, 0);
            acc1 = __builtin_amdgcn_mfma_f32_16x16x32_f16(a1, b, acc1, 0, 0, 0);
        }
    }
    red[w][0][lane] = acc0;
    red[w][1][lane] = acc1;
    __syncthreads();

    // epilogue: 1024 cell values (32 rows x 32 h-cols), 2 per thread
    #pragma unroll
    for (int e = 0; e < 2; ++e) {
        const int idx = tid * 2 + e;
        const int hc = idx & 31, rl = idx >> 5;
        const int mt = rl >> 4, r4 = rl & 15;
        const int lane_e = ((r4 >> 2) << 4) | (hc & 15);
        const int reg = r4 & 3;
        const int colg = i * 32 + hc;
        const int ws = (hc >> 4) * 4;
        const float zi = red[ws + 0][mt][lane_e][reg] + bsum[0 * 1024 + colg];
        const float zf = red[ws + 1][mt][lane_e][reg] + bsum[1 * 1024 + colg];
        const float zg = red[ws + 2][mt][lane_e][reg] + bsum[2 * 1024 + colg];
        const float zo = red[ws + 3][mt][lane_e][reg] + bsum[3 * 1024 + colg];
        const float cn = sigmoidf_(zf) * c2[e] + sigmoidf_(zi) * tanhf(zg);
        c2[e] = cn;
        const int mtile = mtbase + mt;
        const int kb = colg >> 5, q = (colg >> 3) & 3, j = colg & 7;
        h_out[(((size_t)mtile * 32 + kb) * 64 + q * 16 + r4) * 8 + j] =
            f2h(sigmoidf_(zo) * tanhf(cn));
    }
}

// ---------- FC1 phase: U = tanh(h1 @ fc_w1^T + b1), block i owns 32 U-cols ----------
static __device__ __forceinline__ void fc1p(
    const u16* __restrict__ AFx, const u16* __restrict__ BFw,
    const float* __restrict__ bias, u16* __restrict__ U,
    int xcd, int i, int w, int lane, int tid, u16* ldsA, f32x4 (*red)[2][64])
{
    const int mtbase = xcd * 2;
    stage_seg(AFx, 5, mtbase, ldsA, tid);
    __syncthreads();

    // wave w: nt_local = w>>2 (0/1), K-quarter kq = w&3 (8 kb)
    const int ntl = w >> 2, kq = w & 3;
    const int ctq = i >> 1, nt = (i & 1) * 2 + ntl;
    f32x4 acc0 = {0, 0, 0, 0}, acc1 = {0, 0, 0, 0};
    const u16* bp = BFw + (((size_t)(ctq * 4 + nt) * 32) * 64 + lane) * 8;
    #pragma unroll 4
    for (int k = 0; k < 8; ++k) {
        const int kb = kq * 8 + k;
        f16x8 b  = ldfrag(bp + (size_t)kb * 512);
        f16x8 a0 = *(const f16x8*)(ldsA + (((size_t)kb) * 64 + lane) * 8);
        f16x8 a1 = *(const f16x8*)(ldsA + (((size_t)32 + kb) * 64 + lane) * 8);
        acc0 = __builtin_amdgcn_mfma_f32_16x16x32_f16(a0, b, acc0, 0, 0, 0);
        acc1 = __builtin_amdgcn_mfma_f32_16x16x32_f16(a1, b, acc1, 0, 0, 0);
    }
    red[w][0][lane] = acc0;
    red[w][1][lane] = acc1;
    __syncthreads();

    #pragma unroll
    for (int e = 0; e < 2; ++e) {
        const int idx = tid * 2 + e;
        const int uc = idx & 31, rl = idx >> 5;
        const int mt = rl >> 4, r4 = rl & 15;
        const int lane_e = ((r4 >> 2) << 4) | (uc & 15);
        const int reg = r4 & 3;
        const int ntl_e = uc >> 4;
        float z = red[ntl_e * 4 + 0][mt][lane_e][reg] +
                  red[ntl_e * 4 + 1][mt][lane_e][reg] +
                  red[ntl_e * 4 + 2][mt][lane_e][reg] +
                  red[ntl_e * 4 + 3][mt][lane_e][reg];
        const int col = i * 32 + uc;
        z = tanhf(z + bias[col]);
        const int mtile = mtbase + mt;
        const int kb = col >> 5, q = (col >> 3) & 3, j = col & 7;
        U[(((size_t)mtile * 32 + kb) * 64 + q * 16 + r4) * 8 + j] = f2h(z);
    }
}

// ---------- FC2 phase + est feedback: blocks i<4 active (i = nt, 16 cols each) ----------
static __device__ __forceinline__ void fc2p(
    const u16* __restrict__ AFu, const u16* __restrict__ BFw2,
    const float* __restrict__ b2, float* est,
    float* __restrict__ out_t, u16* __restrict__ xdec_t,
    int xcd, int i, int w, int lane, int tid, u16* ldsA, f32x4 (*red)[2][64])
{
    if (i >= 4) return;   // idle blocks go straight to the barrier
    const int mtbase = xcd * 2;
    stage_seg(AFu, 5, mtbase, ldsA, tid);
    __syncthreads();

    // wave w: K-eighth kb in [w*4, w*4+4); nt = i
    f32x4 acc0 = {0, 0, 0, 0}, acc1 = {0, 0, 0, 0};
    const u16* bp = BFw2 + (((size_t)i * 32) * 64 + lane) * 8;
    #pragma unroll
    for (int k = 0; k < 4; ++k) {
        const int kb = w * 4 + k;
        f16x8 b  = ldfrag(bp + (size_t)kb * 512);
        f16x8 a0 = *(const f16x8*)(ldsA + (((size_t)kb) * 64 + lane) * 8);
        f16x8 a1 = *(const f16x8*)(ldsA + (((size_t)32 + kb) * 64 + lane) * 8);
        acc0 = __builtin_amdgcn_mfma_f32_16x16x32_f16(a0, b, acc0, 0, 0, 0);
        acc1 = __builtin_amdgcn_mfma_f32_16x16x32_f16(a1, b, acc1, 0, 0, 0);
    }
    red[w][0][lane] = acc0;
    red[w][1][lane] = acc1;
    __syncthreads();

    // epilogue: 32 rows x 16 cols = 512 values, 1 per thread
    const int rl = tid >> 4, cl = tid & 15;
    const int mt = rl >> 4, r4 = rl & 15;
    const int lane_e = ((r4 >> 2) << 4) | cl;
    const int reg = r4 & 3;
    float z = 0.f;
    #pragma unroll
    for (int p8 = 0; p8 < 8; ++p8) z += red[p8][mt][lane_e][reg];
    const int colg = i * 16 + cl;
    const int rowg = xcd * 32 + rl;
    const float v = z + b2[colg] + *est;
    *est = v;
    out_t[(size_t)rowg * 64 + colg] = v;
    const int cx = 192 + colg;
    const int mtile = mtbase + mt;
    xdec_t[(((size_t)mtile * 8 + (cx >> 5)) * 64 + ((cx >> 3) & 3) * 16 + r4) * 8 + (cx & 7)] = f2h(v);
}

// ---------- persistent kernel ----------
__global__ __launch_bounds__(512, 1) void persist2_k(PP p)
{
    extern __shared__ char smem[];          // 147456 B: A-stage 128K + red 16K
    u16* ldsA = (u16*)smem;
    f32x4 (*red)[2][64] = (f32x4 (*)[2][64])(smem + 131072);

    const int tid  = threadIdx.x;
    const int w    = tid >> 6;
    const int lane = tid & 63;
    const int b    = blockIdx.x;
    const int xcd  = b & 7;      // HW round-robin block->XCD [m09]
    const int i    = b >> 3;     // XCD-local block index 0..31

    unsigned* cnt = p.bar + xcd * 128;
    unsigned* rel = p.bar + xcd * 128 + 64;
    unsigned ep = 0;

    float c0[2] = {0.f, 0.f}, c1[2] = {0.f, 0.f};
    float est = 0.f;
    if (i < 4) {
        const int rl = tid >> 4, cl = tid & 15;
        est = p.pre_y[(size_t)63 * 16384 + (size_t)(xcd * 32 + rl) * 64 + (i * 16 + cl)];
    }

    u16 *h0c = p.h0a, *h0n = p.h0b;
    u16 *h1c = p.h1a, *h1n = p.h1b;

    // --- encode: 64 steps ---
    for (int t = 0; t < 64; ++t) {
        lstm2(p.xyenc + (size_t)t * 65536, 3, p.wih0, h0c, p.whh0,
              p.b0s, c0, h0n, xcd, i, w, lane, tid, ldsA, red);
        xbar(cnt, rel, ep); ++ep;
        lstm2(h0n, 5, p.wih1, h1c, p.whh1,
              p.b1s, c1, h1n, xcd, i, w, lane, tid, ldsA, red);
        xbar(cnt, rel, ep); ++ep;
        u16* tp;
        tp = h0c; h0c = h0n; h0n = tp;
        tp = h1c; h1c = h1n; h1n = tp;
    }
    // --- decode: 48 steps ---
    for (int t = 0; t < 48; ++t) {
        fc1p(h1c, p.fcw1, p.fcb1, p.ufc, xcd, i, w, lane, tid, ldsA, red);
        xbar(cnt, rel, ep); ++ep;
        fc2p(p.ufc, p.fcw2, p.fcb2, &est,
             p.out + (size_t)t * 16384, p.xdec + (size_t)t * 65536,
             xcd, i, w, lane, tid, ldsA, red);
        xbar(cnt, rel, ep); ++ep;
        if (t < 47) {
            lstm2(p.xdec + (size_t)t * 65536, 3, p.wih0, h0c, p.whh0,
                  p.b0s, c0, h0n, xcd, i, w, lane, tid, ldsA, red);
            xbar(cnt, rel, ep); ++ep;
            lstm2(h0n, 5, p.wih1, h1c, p.whh1,
                  p.b1s, c1, h1n, xcd, i, w, lane, tid, ldsA, red);
            xbar(cnt, rel, ep); ++ep;
            u16* tp;
            tp = h0c; h0c = h0n; h0n = tp;
            tp = h1c; h1c = h1n; h1n = tp;
        }
    }
}

// ---------- setup kernels ----------
__global__ void cvt_bfrag_k(const float* __restrict__ src, u16* __restrict__ dst,
                            int K, int kbshift, int S1, int S2, int total) {
    int i = blockIdx.x * 256 + threadIdx.x;
    if (i >= total) return;
    const int lane = i & 63;
    const int kb   = (i >> 6) & ((1 << kbshift) - 1);
    const int rest = i >> (6 + kbshift);
    const int sub  = rest & 3;
    const int grp  = rest >> 2;
    const int row  = sub * S1 + grp * S2 + (lane & 15);
    const int colK = kb * 32 + (lane >> 4) * 8;
    const float* s = src + (size_t)row * K + colK;
    u16* d = dst + (size_t)i * 8;
    #pragma unroll
    for (int j = 0; j < 8; ++j) d[j] = f2h(s[j]);
}
__global__ void bias_k(const float* __restrict__ a, const float* __restrict__ b,
                       float* __restrict__ d, int n) {
    int i = blockIdx.x * 256 + threadIdx.x;
    if (i < n) d[i] = a[i] + b[i];
}
__global__ void zeroh_k(u16* h0, u16* h1, unsigned* bar) {   // n = 256*1024
    int i = blockIdx.x * 256 + threadIdx.x;
    h0[i] = 0; h1[i] = 0;
    if (i < 1024) bar[i] = 0u;
}
__global__ void pack_enc_k(const float* __restrict__ pre_x, const float* __restrict__ pre_y,
                           u16* __restrict__ xy) {   // threads = 64*16*8*64
    int i = blockIdx.x * 256 + threadIdx.x;
    const int lane  = i & 63;
    const int kb    = (i >> 6) & 7;
    const int mtile = (i >> 9) & 15;
    const int t     = i >> 13;
    const int row   = mtile * 16 + (lane & 15);
    const int cb    = kb * 32 + (lane >> 4) * 8;
    u16* d = xy + (size_t)i * 8;
    #pragma unroll
    for (int j = 0; j < 8; ++j) {
        const int col = cb + j;
        const float v = (col < 192) ? pre_x[((size_t)t * 256 + row) * 192 + col]
                                    : pre_y[((size_t)t * 256 + row) * 64 + (col - 192)];
        d[j] = f2h(v);
    }
}
__global__ void pack_dec_k(const float* __restrict__ fx, u16* __restrict__ xd,
                           int total_threads) {      // threads = 48*16*6*64
    int i = blockIdx.x * 256 + threadIdx.x;
    if (i >= total_threads) return;
    const int lane  = i & 63;
    int rest = i >> 6;
    const int kb    = rest % 6;  rest /= 6;
    const int mtile = rest & 15;
    const int t     = rest >> 4;
    const int row   = mtile * 16 + (lane & 15);
    const int cb    = kb * 32 + (lane >> 4) * 8;
    u16* d = xd + ((((size_t)t * 16 + mtile) * 8 + kb) * 64 + lane) * 8;
    #pragma unroll
    for (int j = 0; j < 8; ++j)
        d[j] = f2h(fx[((size_t)t * 256 + row) * 192 + cb + j]);
}

extern "C" void kernel_launch(void* const* d_in, const int* in_sizes, int n_in,
                              void* d_out, int out_size, void* d_ws, size_t ws_size,
                              hipStream_t stream) {
    const float* pre_x  = (const float*)d_in[0];
    const float* pre_y  = (const float*)d_in[1];
    const float* fx     = (const float*)d_in[2];
    const float* w_ih_0 = (const float*)d_in[3];
    const float* w_hh_0 = (const float*)d_in[4];
    const float* b_ih_0 = (const float*)d_in[5];
    const float* b_hh_0 = (const float*)d_in[6];
    const float* w_ih_1 = (const float*)d_in[7];
    const float* w_hh_1 = (const float*)d_in[8];
    const float* b_ih_1 = (const float*)d_in[9];
    const float* b_hh_1 = (const float*)d_in[10];
    const float* fc_w1  = (const float*)d_in[11];
    const float* fc_b1  = (const float*)d_in[12];
    const float* fc_w2  = (const float*)d_in[13];
    const float* fc_b2  = (const float*)d_in[14];

    size_t off = 0;
    char* wsb = (char*)d_ws;
    auto alloc = [&](size_t bytes) -> void* {
        void* p = wsb + off;
        off += (bytes + 255) & ~(size_t)255;
        return p;
    };
    u16* wih0 = (u16*)alloc((size_t)4096 * 256 * 2);
    u16* whh0 = (u16*)alloc((size_t)4096 * 1024 * 2);
    u16* wih1 = (u16*)alloc((size_t)4096 * 1024 * 2);
    u16* whh1 = (u16*)alloc((size_t)4096 * 1024 * 2);
    u16* fcw1 = (u16*)alloc((size_t)1024 * 1024 * 2);
    u16* fcw2 = (u16*)alloc((size_t)64 * 1024 * 2);
    float* b0s = (float*)alloc(4096 * 4);
    float* b1s = (float*)alloc(4096 * 4);
    u16* xyenc = (u16*)alloc((size_t)64 * 256 * 256 * 2);
    u16* xdec  = (u16*)alloc((size_t)48 * 256 * 256 * 2);
    u16* h0a = (u16*)alloc((size_t)256 * 1024 * 2);
    u16* h0b = (u16*)alloc((size_t)256 * 1024 * 2);
    u16* h1a = (u16*)alloc((size_t)256 * 1024 * 2);
    u16* h1b = (u16*)alloc((size_t)256 * 1024 * 2);
    u16* ufc = (u16*)alloc((size_t)256 * 1024 * 2);
    unsigned* bar = (unsigned*)alloc(4096);

    // --- setup ---
    cvt_bfrag_k<<<512, 256, 0, stream>>>(w_ih_0, wih0, 256, 3, 1024, 16, 64 * 4 * 8 * 64);
    cvt_bfrag_k<<<2048, 256, 0, stream>>>(w_hh_0, whh0, 1024, 5, 1024, 16, 64 * 4 * 32 * 64);
    cvt_bfrag_k<<<2048, 256, 0, stream>>>(w_ih_1, wih1, 1024, 5, 1024, 16, 64 * 4 * 32 * 64);
    cvt_bfrag_k<<<2048, 256, 0, stream>>>(w_hh_1, whh1, 1024, 5, 1024, 16, 64 * 4 * 32 * 64);
    cvt_bfrag_k<<<512, 256, 0, stream>>>(fc_w1, fcw1, 1024, 5, 16, 64, 16 * 4 * 32 * 64);
    cvt_bfrag_k<<<32, 256, 0, stream>>>(fc_w2, fcw2, 1024, 5, 16, 0, 1 * 4 * 32 * 64);
    bias_k<<<16, 256, 0, stream>>>(b_ih_0, b_hh_0, b0s, 4096);
    bias_k<<<16, 256, 0, stream>>>(b_ih_1, b_hh_1, b1s, 4096);
    zeroh_k<<<1024, 256, 0, stream>>>(h0a, h1a, bar);
    pack_enc_k<<<2048, 256, 0, stream>>>(pre_x, pre_y, xyenc);
    pack_dec_k<<<1152, 256, 0, stream>>>(fx, xdec, 48 * 16 * 6 * 64);

    // --- persistent recurrence ---
    PP p;
    p.xyenc = xyenc; p.xdec = xdec;
    p.wih0 = wih0; p.whh0 = whh0; p.wih1 = wih1; p.whh1 = whh1;
    p.fcw1 = fcw1; p.fcw2 = fcw2;
    p.b0s = b0s; p.b1s = b1s; p.fcb1 = fc_b1; p.fcb2 = fc_b2; p.pre_y = pre_y;
    p.h0a = h0a; p.h0b = h0b; p.h1a = h1a; p.h1b = h1b; p.ufc = ufc;
    p.out = (float*)d_out;
    p.bar = bar;

    static bool attr_set = false;
    if (!attr_set) {
        hipFuncSetAttribute((const void*)persist2_k,
                            hipFuncAttributeMaxDynamicSharedMemorySize, 147456);
        attr_set = true;
    }

    void* args[] = { &p };
    hipLaunchCooperativeKernel((const void*)persist2_k, dim3(256), dim3(512),
                               args, 147456, stream);
}

// Round 6
// 3740.614 us; speedup vs baseline: 1.1838x; 1.1838x over previous
//
#include <hip/hip_runtime.h>
#include <stdint.h>

typedef unsigned short u16;
typedef __attribute__((ext_vector_type(8))) _Float16 f16x8;
typedef __attribute__((ext_vector_type(4))) float f32x4;

// ---------- helpers ----------
__device__ inline f16x8 ldfrag(const u16* p) { return *(const f16x8*)p; }
// device-scope write-through store (visible in L3 after vmcnt drain)
__device__ __forceinline__ void st_u16_dc(u16* p, u16 v) {
    unsigned vv = v;
    asm volatile("global_store_short %0, %1, off sc1" :: "v"(p), "v"(vv) : "memory");
}
__device__ inline u16 f2h(float x) {
    _Float16 h = (_Float16)x;
    union { _Float16 h; u16 u; } v; v.h = h;
    return v.u;
}
__device__ inline float sigmoidf_(float x) { return 1.0f / (1.0f + expf(-x)); }

// flat grid barrier (proven R4): monotonic counter + release word, relaxed
// agent atomics; no cache maintenance -> L2 stays warm. Correctness of data
// exchange comes from: sc1 write-through stores + t-unique plain-read buffers.
__device__ __forceinline__ void gbar(unsigned* cnt, unsigned* rel, unsigned ep) {
    __syncthreads();   // drains all waves' vmem (sc1 stores reach L3)
    if (threadIdx.x == 0) {
        unsigned old = __hip_atomic_fetch_add(cnt, 1u, __ATOMIC_RELAXED,
                                              __HIP_MEMORY_SCOPE_AGENT);
        if (old == ep * 256u + 255u) {
            __hip_atomic_store(rel, ep + 1u, __ATOMIC_RELAXED,
                               __HIP_MEMORY_SCOPE_AGENT);
        } else {
            unsigned r;
            do {
                __builtin_amdgcn_s_sleep(8);
                r = __hip_atomic_load(rel, __ATOMIC_RELAXED,
                                      __HIP_MEMORY_SCOPE_AGENT);
            } while (r < ep + 1u);
        }
    }
    __syncthreads();
    asm volatile("" ::: "memory");
}

// Layouts (fp16 as u16):
//  A-frag (X: 256 x K):  AF[mtile][kb][lane][8]
//      = X[mtile*16 + (lane&15)][kb*32 + (lane>>4)*8 + j]
//  B-frag (W: N x K):    BF[grp][sub][kb][lane][8]
//      = W[row(grp,sub,lane)][kb*32 + (lane>>4)*8 + j],  row = sub*S1 + grp*S2 + (lane&15)
//  lstm:  S1=1024 (gate), S2=16 (ct)   -> BF[ct][gate][kb][..]
//  fc1:   S1=16,  S2=64                -> BF[ctq][nt ][kb][..]
//  fc2:   S1=16,  S2=0 (grp=0)         -> BF[0][nt][kb][..]
//
// COLUMN-PARTITIONED (R4 tiling) + T-UNIQUE ACTIVATION RINGS (this round):
//  block b: ct = b&63, mg = b>>6; XCD = b&7 = ct&7 -> per-XCD weight slice
//  ~3.6 MB (disjoint, L2-resident). All dynamic activations (h0, h1, ufc)
//  live in per-step rings: writers use sc1 (write-through), readers use PLAIN
//  cached loads of never-before-cached addresses -> L2 miss -> fresh from L3,
//  then L2-hits for the other blocks on the same XCD (free dedup).

struct PP {
    const u16* xyenc;
    u16* xdec;
    const u16 *wih0, *whh0, *wih1, *whh1, *fcw1, *fcw2;
    const float *b0s, *b1s, *fcb1, *fcb2, *pre_y;
    const u16 *h0init, *h1init;
    u16 *h0ring, *h1ring, *ufcring;   // 111 / 111 / 48 steps x 256x1024 u16
    float* out;
    unsigned *cnt, *rel;
};

// ---------- LSTM cell phase (ct = b&63, mg = b>>6) ----------
// 512 threads = 8 waves, 8-way K-split; two-stage LDS reduction; c in regs.
static __device__ __forceinline__ void lstm_phase(
    const u16* __restrict__ AFa, int KBa, const u16* __restrict__ BFa,
    const u16* __restrict__ AFh, const u16* __restrict__ BFh,
    const float* __restrict__ bsum, float* creg, u16* __restrict__ h_out,
    int ct, int mg, int w, int lane, f32x4 (*red)[16][64])
{
    const int l15  = lane & 15;
    const int quad = lane >> 4;

    f32x4 acc[4][4];
    #pragma unroll
    for (int t = 0; t < 4; ++t)
        #pragma unroll
        for (int g = 0; g < 4; ++g) acc[t][g] = (f32x4){0, 0, 0, 0};

    // phase A: x-side, wave w takes kb in [w*q, w*q+q), q = KBa/8
    {
        const int q = KBa >> 3;
        #pragma unroll 2
        for (int kb = w * q; kb < w * q + q; ++kb) {
            f16x8 a[4], b[4];
            #pragma unroll
            for (int t = 0; t < 4; ++t)
                a[t] = ldfrag(AFa + (((size_t)(mg * 4 + t) * KBa + kb) * 64 + lane) * 8);
            #pragma unroll
            for (int g = 0; g < 4; ++g)
                b[g] = ldfrag(BFa + (((size_t)(ct * 4 + g) * KBa + kb) * 64 + lane) * 8);
            #pragma unroll
            for (int t = 0; t < 4; ++t)
                #pragma unroll
                for (int g = 0; g < 4; ++g)
                    acc[t][g] = __builtin_amdgcn_mfma_f32_16x16x32_f16(a[t], b[g], acc[t][g], 0, 0, 0);
        }
    }
    // phase B: h-side, KB=32, eighth = 4
    {
        #pragma unroll 2
        for (int kb = w * 4; kb < w * 4 + 4; ++kb) {
            f16x8 a[4], b[4];
            #pragma unroll
            for (int t = 0; t < 4; ++t)
                a[t] = ldfrag(AFh + (((size_t)(mg * 4 + t) * 32 + kb) * 64 + lane) * 8);
            #pragma unroll
            for (int g = 0; g < 4; ++g)
                b[g] = ldfrag(BFh + (((size_t)(ct * 4 + g) * 32 + kb) * 64 + lane) * 8);
            #pragma unroll
            for (int t = 0; t < 4; ++t)
                #pragma unroll
                for (int g = 0; g < 4; ++g)
                    acc[t][g] = __builtin_amdgcn_mfma_f32_16x16x32_f16(a[t], b[g], acc[t][g], 0, 0, 0);
        }
    }

    // two-stage cross-wave K-reduction (8 partials -> 4 -> sum)
    if (w >= 4) {
        #pragma unroll
        for (int t = 0; t < 4; ++t)
            #pragma unroll
            for (int g = 0; g < 4; ++g)
                red[w - 4][t * 4 + g][lane] = acc[t][g];
    }
    __syncthreads();
    if (w < 4) {
        #pragma unroll
        for (int t = 0; t < 4; ++t)
            #pragma unroll
            for (int g = 0; g < 4; ++g)
                red[w][t * 4 + g][lane] += acc[t][g];
    }
    __syncthreads();
    if (w < 4) {
        // wave w owns mt = mg*4 + w
        f32x4 z[4];
        #pragma unroll
        for (int g = 0; g < 4; ++g)
            z[g] = red[0][w * 4 + g][lane] + red[1][w * 4 + g][lane] +
                   red[2][w * 4 + g][lane] + red[3][w * 4 + g][lane];

        const int col   = ct * 16 + l15;
        const int mtile = mg * 4 + w;
        float bv[4];
        #pragma unroll
        for (int g = 0; g < 4; ++g) bv[g] = bsum[g * 1024 + col];
        const int hkb = col >> 5, hquad = (col >> 3) & 3, hj = col & 7;
        #pragma unroll
        for (int r = 0; r < 4; ++r) {
            const int rl = quad * 4 + r;
            const float zi = z[0][r] + bv[0];
            const float zf = z[1][r] + bv[1];
            const float zg = z[2][r] + bv[2];
            const float zo = z[3][r] + bv[3];
            const float cv = creg[r];
            const float cn = sigmoidf_(zf) * cv + sigmoidf_(zi) * tanhf(zg);
            creg[r] = cn;
            st_u16_dc(h_out + (((size_t)mtile * 32 + hkb) * 64 + hquad * 16 + rl) * 8 + hj,
                      f2h(sigmoidf_(zo) * tanhf(cn)));
        }
    }
}

// ---------- FC1 phase: U = tanh(h1 @ fc_w1^T + b1) ----------
// 256 blocks: mt = b>>4 (0..15), ctq = b&15; 8 waves 8-way K-split.
static __device__ __forceinline__ void fc1_phase(
    const u16* __restrict__ AFx, const u16* __restrict__ BFw,
    const float* __restrict__ bias, u16* __restrict__ U,
    int b, int w, int lane, f32x4 (*red)[16][64])
{
    const int mt = b >> 4, ctq = b & 15;
    const int l15 = lane & 15, quad = lane >> 4;
    f32x4 acc[4];
    #pragma unroll
    for (int g = 0; g < 4; ++g) acc[g] = (f32x4){0, 0, 0, 0};

    #pragma unroll
    for (int k = 0; k < 4; ++k) {
        const int kb = w * 4 + k;
        f16x8 a = ldfrag(AFx + (((size_t)mt * 32 + kb) * 64 + lane) * 8);
        #pragma unroll
        for (int g = 0; g < 4; ++g) {
            f16x8 bb = ldfrag(BFw + (((size_t)(ctq * 4 + g) * 32 + kb) * 64 + lane) * 8);
            acc[g] = __builtin_amdgcn_mfma_f32_16x16x32_f16(a, bb, acc[g], 0, 0, 0);
        }
    }

    f32x4 (*r8)[4][64] = (f32x4 (*)[4][64])red;   // [8][4][64]
    #pragma unroll
    for (int g = 0; g < 4; ++g) r8[w][g][lane] = acc[g];
    __syncthreads();
    if (w < 4) {
        f32x4 z = r8[0][w][lane];
        #pragma unroll
        for (int p = 1; p < 8; ++p) z += r8[p][w][lane];
        const int col = ctq * 64 + w * 16 + l15;
        const float bv = bias[col];
        const int ukb = col >> 5, uq = (col >> 3) & 3, uj = col & 7;
        #pragma unroll
        for (int r = 0; r < 4; ++r) {
            const int rl = quad * 4 + r;
            st_u16_dc(U + (((size_t)mt * 32 + ukb) * 64 + uq * 16 + rl) * 8 + uj,
                      f2h(tanhf(z[r] + bv)));
        }
    }
}

// ---------- FC2 phase + est feedback (blocks b<64: mt = b>>2, cg = b&3) ----------
static __device__ __forceinline__ void fc2_phase(
    const u16* __restrict__ AFu, const u16* __restrict__ BFw2,
    const float* __restrict__ b2, float* estreg,
    float* __restrict__ out_t, u16* __restrict__ xdec_t,
    int b, int w, int lane, f32x4 (*red)[16][64])
{
    f32x4 (*rr)[64] = (f32x4 (*)[64])red;   // [8][64]
    const int l15 = lane & 15, quad = lane >> 4;
    const int mt = b >> 2, cg = b & 3;
    if (b < 64) {
        f32x4 acc = (f32x4){0, 0, 0, 0};
        #pragma unroll
        for (int k = 0; k < 4; ++k) {
            const int kb = w * 4 + k;
            f16x8 a = ldfrag(AFu + (((size_t)mt * 32 + kb) * 64 + lane) * 8);
            f16x8 bb = ldfrag(BFw2 + (((size_t)cg * 32 + kb) * 64 + lane) * 8);
            acc = __builtin_amdgcn_mfma_f32_16x16x32_f16(a, bb, acc, 0, 0, 0);
        }
        rr[w][lane] = acc;
    }
    __syncthreads();
    if (b < 64 && w == 0) {
        f32x4 acc = rr[0][lane];
        #pragma unroll
        for (int p = 1; p < 8; ++p) acc += rr[p][lane];
        const int col = cg * 16 + l15;
        const float bv = b2[col];
        const int cx = 192 + col;
        const int xkb = cx >> 5, xq = (cx >> 3) & 3, xj = cx & 7;
        #pragma unroll
        for (int r = 0; r < 4; ++r) {
            const int rl = quad * 4 + r;
            const int row = mt * 16 + rl;
            const float v = acc[r] + bv + estreg[r];
            estreg[r] = v;
            out_t[row * 64 + col] = v;   // host-visible only; flushed at kernel end
            st_u16_dc(xdec_t + (((size_t)mt * 8 + xkb) * 64 + xq * 16 + rl) * 8 + xj, f2h(v));
        }
    }
}

// ---------- persistent kernel: whole recurrence, t-unique rings ----------
__global__ __launch_bounds__(512, 2) void persist_k(PP p)
{
    __shared__ f32x4 red[4][16][64];   // 64 KB, reused by every phase

    const int tid  = threadIdx.x;
    const int w    = tid >> 6;
    const int lane = tid & 63;
    const int l15  = lane & 15;
    const int quad = lane >> 4;
    const int b    = blockIdx.x;       // 0..255
    const int ct   = b & 63;
    const int mg   = b >> 6;

    unsigned ep = 0;

    float c0reg[4] = {0.f, 0.f, 0.f, 0.f};
    float c1reg[4] = {0.f, 0.f, 0.f, 0.f};
    float estreg[4] = {0.f, 0.f, 0.f, 0.f};
    if (b < 64) {   // only fc2-active blocks own est state
        const int fmt = b >> 2, fcg = b & 3;
        #pragma unroll
        for (int r = 0; r < 4; ++r) {
            const int row = fmt * 16 + quad * 4 + r;
            const int col = fcg * 16 + l15;
            estreg[r] = p.pre_y[(size_t)63 * 16384 + row * 64 + col];  // pre_y[-1]
        }
    }

    const size_t HS = 262144;   // 256*1024 u16 per ring slot
    const u16* h0prev = p.h0init;
    const u16* h1prev = p.h1init;

    // --- encode: 64 steps ---
    for (int t = 0; t < 64; ++t) {
        u16* h0cur = p.h0ring + (size_t)t * HS;
        lstm_phase(p.xyenc + (size_t)t * 65536, 8, p.wih0, h0prev, p.whh0,
                   p.b0s, c0reg, h0cur, ct, mg, w, lane, red);
        gbar(p.cnt, p.rel, ep); ++ep;
        u16* h1cur = p.h1ring + (size_t)t * HS;
        lstm_phase(h0cur, 32, p.wih1, h1prev, p.whh1,
                   p.b1s, c1reg, h1cur, ct, mg, w, lane, red);
        gbar(p.cnt, p.rel, ep); ++ep;
        h0prev = h0cur; h1prev = h1cur;
    }

    // --- decode: 48 steps; last step needs only fc1+fc2 ---
    for (int t = 0; t < 48; ++t) {
        u16* ufct = p.ufcring + (size_t)t * HS;
        fc1_phase(h1prev, p.fcw1, p.fcb1, ufct, b, w, lane, red);
        gbar(p.cnt, p.rel, ep); ++ep;
        fc2_phase(ufct, p.fcw2, p.fcb2, estreg,
                  p.out + (size_t)t * 16384, p.xdec + (size_t)t * 65536,
                  b, w, lane, red);
        gbar(p.cnt, p.rel, ep); ++ep;
        if (t < 47) {
            u16* h0cur = p.h0ring + (size_t)(64 + t) * HS;
            lstm_phase(p.xdec + (size_t)t * 65536, 8, p.wih0, h0prev, p.whh0,
                       p.b0s, c0reg, h0cur, ct, mg, w, lane, red);
            gbar(p.cnt, p.rel, ep); ++ep;
            u16* h1cur = p.h1ring + (size_t)(64 + t) * HS;
            lstm_phase(h0cur, 32, p.wih1, h1prev, p.whh1,
                       p.b1s, c1reg, h1cur, ct, mg, w, lane, red);
            gbar(p.cnt, p.rel, ep); ++ep;
            h0prev = h0cur; h1prev = h1cur;
        }
    }
}

// ---------- setup kernels ----------
__global__ void cvt_bfrag_k(const float* __restrict__ src, u16* __restrict__ dst,
                            int K, int kbshift, int S1, int S2, int total) {
    int i = blockIdx.x * 256 + threadIdx.x;
    if (i >= total) return;
    const int lane = i & 63;
    const int kb   = (i >> 6) & ((1 << kbshift) - 1);
    const int rest = i >> (6 + kbshift);
    const int sub  = rest & 3;
    const int grp  = rest >> 2;
    const int row  = sub * S1 + grp * S2 + (lane & 15);
    const int colK = kb * 32 + (lane >> 4) * 8;
    const float* s = src + (size_t)row * K + colK;
    u16* d = dst + (size_t)i * 8;
    #pragma unroll
    for (int j = 0; j < 8; ++j) d[j] = f2h(s[j]);
}
__global__ void bias_k(const float* __restrict__ a, const float* __restrict__ b,
                       float* __restrict__ d, int n) {
    int i = blockIdx.x * 256 + threadIdx.x;
    if (i < n) d[i] = a[i] + b[i];
}
__global__ void zeroh_k(u16* h0i, u16* h1i, unsigned* bar) {   // n = 256*1024
    int i = blockIdx.x * 256 + threadIdx.x;
    h0i[i] = 0; h1i[i] = 0;
    if (i < 128) bar[i] = 0u;
}
__global__ void pack_enc_k(const float* __restrict__ pre_x, const float* __restrict__ pre_y,
                           u16* __restrict__ xy) {   // threads = 64*16*8*64
    int i = blockIdx.x * 256 + threadIdx.x;
    const int lane  = i & 63;
    const int kb    = (i >> 6) & 7;
    const int mtile = (i >> 9) & 15;
    const int t     = i >> 13;
    const int row   = mtile * 16 + (lane & 15);
    const int cb    = kb * 32 + (lane >> 4) * 8;
    u16* d = xy + (size_t)i * 8;
    #pragma unroll
    for (int j = 0; j < 8; ++j) {
        const int col = cb + j;
        const float v = (col < 192) ? pre_x[((size_t)t * 256 + row) * 192 + col]
                                    : pre_y[((size_t)t * 256 + row) * 64 + (col - 192)];
        d[j] = f2h(v);
    }
}
__global__ void pack_dec_k(const float* __restrict__ fx, u16* __restrict__ xd,
                           int total_threads) {      // threads = 48*16*6*64
    int i = blockIdx.x * 256 + threadIdx.x;
    if (i >= total_threads) return;
    const int lane  = i & 63;
    int rest = i >> 6;
    const int kb    = rest % 6;  rest /= 6;
    const int mtile = rest & 15;
    const int t     = rest >> 4;
    const int row   = mtile * 16 + (lane & 15);
    const int cb    = kb * 32 + (lane >> 4) * 8;
    u16* d = xd + ((((size_t)t * 16 + mtile) * 8 + kb) * 64 + lane) * 8;
    #pragma unroll
    for (int j = 0; j < 8; ++j)
        d[j] = f2h(fx[((size_t)t * 256 + row) * 192 + cb + j]);
}

extern "C" void kernel_launch(void* const* d_in, const int* in_sizes, int n_in,
                              void* d_out, int out_size, void* d_ws, size_t ws_size,
                              hipStream_t stream) {
    const float* pre_x  = (const float*)d_in[0];
    const float* pre_y  = (const float*)d_in[1];
    const float* fx     = (const float*)d_in[2];
    const float* w_ih_0 = (const float*)d_in[3];
    const float* w_hh_0 = (const float*)d_in[4];
    const float* b_ih_0 = (const float*)d_in[5];
    const float* b_hh_0 = (const float*)d_in[6];
    const float* w_ih_1 = (const float*)d_in[7];
    const float* w_hh_1 = (const float*)d_in[8];
    const float* b_ih_1 = (const float*)d_in[9];
    const float* b_hh_1 = (const float*)d_in[10];
    const float* fc_w1  = (const float*)d_in[11];
    const float* fc_b1  = (const float*)d_in[12];
    const float* fc_w2  = (const float*)d_in[13];
    const float* fc_b2  = (const float*)d_in[14];

    size_t off = 0;
    char* wsb = (char*)d_ws;
    auto alloc = [&](size_t bytes) -> void* {
        void* p = wsb + off;
        off += (bytes + 255) & ~(size_t)255;
        return p;
    };
    u16* wih0 = (u16*)alloc((size_t)4096 * 256 * 2);
    u16* whh0 = (u16*)alloc((size_t)4096 * 1024 * 2);
    u16* wih1 = (u16*)alloc((size_t)4096 * 1024 * 2);
    u16* whh1 = (u16*)alloc((size_t)4096 * 1024 * 2);
    u16* fcw1 = (u16*)alloc((size_t)1024 * 1024 * 2);
    u16* fcw2 = (u16*)alloc((size_t)64 * 1024 * 2);
    float* b0s = (float*)alloc(4096 * 4);
    float* b1s = (float*)alloc(4096 * 4);
    u16* xyenc = (u16*)alloc((size_t)64 * 256 * 256 * 2);      // 8 MB
    u16* xdec  = (u16*)alloc((size_t)48 * 256 * 256 * 2);      // 6 MB
    u16* h0init = (u16*)alloc((size_t)256 * 1024 * 2);
    u16* h1init = (u16*)alloc((size_t)256 * 1024 * 2);
    u16* h0ring = (u16*)alloc((size_t)111 * 256 * 1024 * 2);   // 55.5 MB
    u16* h1ring = (u16*)alloc((size_t)111 * 256 * 1024 * 2);   // 55.5 MB
    u16* ufcring = (u16*)alloc((size_t)48 * 256 * 1024 * 2);   // 24 MB
    unsigned* bar = (unsigned*)alloc(512);

    // --- setup ---
    cvt_bfrag_k<<<512, 256, 0, stream>>>(w_ih_0, wih0, 256, 3, 1024, 16, 64 * 4 * 8 * 64);
    cvt_bfrag_k<<<2048, 256, 0, stream>>>(w_hh_0, whh0, 1024, 5, 1024, 16, 64 * 4 * 32 * 64);
    cvt_bfrag_k<<<2048, 256, 0, stream>>>(w_ih_1, wih1, 1024, 5, 1024, 16, 64 * 4 * 32 * 64);
    cvt_bfrag_k<<<2048, 256, 0, stream>>>(w_hh_1, whh1, 1024, 5, 1024, 16, 64 * 4 * 32 * 64);
    cvt_bfrag_k<<<512, 256, 0, stream>>>(fc_w1, fcw1, 1024, 5, 16, 64, 16 * 4 * 32 * 64);
    cvt_bfrag_k<<<32, 256, 0, stream>>>(fc_w2, fcw2, 1024, 5, 16, 0, 1 * 4 * 32 * 64);
    bias_k<<<16, 256, 0, stream>>>(b_ih_0, b_hh_0, b0s, 4096);
    bias_k<<<16, 256, 0, stream>>>(b_ih_1, b_hh_1, b1s, 4096);
    zeroh_k<<<1024, 256, 0, stream>>>(h0init, h1init, bar);
    pack_enc_k<<<2048, 256, 0, stream>>>(pre_x, pre_y, xyenc);
    pack_dec_k<<<1152, 256, 0, stream>>>(fx, xdec, 48 * 16 * 6 * 64);

    // --- persistent recurrence ---
    PP p;
    p.xyenc = xyenc; p.xdec = xdec;
    p.wih0 = wih0; p.whh0 = whh0; p.wih1 = wih1; p.whh1 = whh1;
    p.fcw1 = fcw1; p.fcw2 = fcw2;
    p.b0s = b0s; p.b1s = b1s; p.fcb1 = fc_b1; p.fcb2 = fc_b2; p.pre_y = pre_y;
    p.h0init = h0init; p.h1init = h1init;
    p.h0ring = h0ring; p.h1ring = h1ring; p.ufcring = ufcring;
    p.out = (float*)d_out;
    p.cnt = bar; p.rel = bar + 64;

    void* args[] = { &p };
    hipLaunchCooperativeKernel((const void*)persist_k, dim3(256), dim3(512),
                               args, 0, stream);
}